// Round 10
// baseline (326.231 us; speedup 1.0000x reference)
//
#include <hip/hip_runtime.h>

// ---------------- problem constants ----------------
constexpr int Bc   = 2;
constexpr int Tc   = 2048;
constexpr int Cc   = 1024;   // D_IN
constexpr int QDc  = 1024;   // query dim
constexpr int Hc   = 4;
constexpr int KD2c = 256;
constexpr int BLKc = 128;    // BLOCK (row keys)
constexpr int COLc = 512;    // col keys
constexpr int DOUTc= 512;
constexpr int KSELc= 256;    // top-k per row
constexpr int NKEYS= BLKc + COLc; // 640
constexpr int NBINS= Bc * Tc;     // 4096
constexpr int NSEL = Bc * Hc * BLKc * KSELc; // 262144
constexpr int MAXCHUNKS = 8192;

typedef short bf16x8 __attribute__((ext_vector_type(8)));
typedef float f32x4  __attribute__((ext_vector_type(4)));

// ---------------- bf16 3-way split helpers ----------------
__device__ __forceinline__ unsigned short f2bf(float f) {
    unsigned u = __float_as_uint(f);
    u += 0x7FFFu + ((u >> 16) & 1u);        // round-to-nearest-even
    return (unsigned short)(u >> 16);
}
__device__ __forceinline__ float bf2f(unsigned short h) {
    return __uint_as_float((unsigned)h << 16);
}
__device__ __forceinline__ void splitbf3(float f, unsigned short* h,
                                         unsigned short* m, unsigned short* l) {
    unsigned short hh = f2bf(f);
    float r1 = f - bf2f(hh);
    unsigned short mm = f2bf(r1);
    float r2 = r1 - bf2f(mm);
    *h = hh; *m = mm; *l = f2bf(r2);
}

__device__ __forceinline__ void gld_lds16(const void* g, void* l) {
    __builtin_amdgcn_global_load_lds(
        (const __attribute__((address_space(1))) unsigned int*)g,
        (__attribute__((address_space(3))) unsigned int*)l, 16, 0, 0);
}

// ---------------- conv: causal depthwise k=3, bf16 h/m/l output ----------------
__global__ __launch_bounds__(256) void conv_kernel(
    const float* __restrict__ x, const float* __restrict__ cw,
    const float* __restrict__ cb, unsigned short* __restrict__ y1,
    unsigned short* __restrict__ y2, unsigned short* __restrict__ y3)
{
    int idx = blockIdx.x * 256 + threadIdx.x;       // over B*T*C = 2^22
    int c = idx & (Cc - 1);
    int t = (idx >> 10) & (Tc - 1);
    int b = idx >> 21;
    float w0 = cw[c*3+0], w1 = cw[c*3+1], w2 = cw[c*3+2];
    const float* xb = x + (size_t)b * Tc * Cc;
    float acc = cb[c] + w2 * xb[(size_t)t*Cc + c];
    if (t >= 1) acc += w1 * xb[(size_t)(t-1)*Cc + c];
    if (t >= 2) acc += w0 * xb[(size_t)(t-2)*Cc + c];
    splitbf3(acc, &y1[idx], &y2[idx], &y3[idx]);
}

// ---------------- convert lin_w to h/m/l bf16 ----------------
__global__ __launch_bounds__(256) void convw_kernel(
    const float* __restrict__ w, unsigned short* __restrict__ w1,
    unsigned short* __restrict__ w2, unsigned short* __restrict__ w3)
{
    int idx = blockIdx.x * 256 + threadIdx.x;   // 1M elems
    splitbf3(w[idx], &w1[idx], &w2[idx], &w3[idx]);
}

// ---------------- convert keys to [h][640][256] h/m/l bf16 ----------------
__global__ __launch_bounds__(256) void convkeys_kernel(
    const float* __restrict__ rowkeys, const float* __restrict__ colkeys,
    unsigned short* __restrict__ k1, unsigned short* __restrict__ k2,
    unsigned short* __restrict__ k3)
{
    int bid = blockIdx.x;          // 0..2559 : h*640+n
    int h = bid / NKEYS, n = bid % NKEYS;
    int k = threadIdx.x;           // 0..255
    float v = (n < BLKc) ? rowkeys[((size_t)n*Hc + h)*KD2c + k]
                         : colkeys[((size_t)(n-BLKc)*Hc + h)*KD2c + k];
    size_t o = ((size_t)h*NKEYS + n)*KD2c + k;
    splitbf3(v, &k1[o], &k2[o], &k3[o]);
}

// ---------------- split-bf16(x3) MFMA GEMM core ----------------
// 64x128 tile, 8 waves (wave-tile 32x32), K-step 32, double-buffered.
// LDS per buffer 36KB: A1 0, A2 4K, A3 8K, B1 12K, B2 20K, B3 28K.
// swizzle: chunk (row, slot) holds k-group (slot ^ ((row>>1)&3)).
// Waves 0-3 stage A (3 loads) + B (3 loads) -> vmcnt(6); waves 4-7 stage B only -> vmcnt(3).
__device__ __forceinline__ void mfma_gemm_tile(
    const unsigned short* __restrict__ A1g, const unsigned short* __restrict__ A2g,
    const unsigned short* __restrict__ A3g, int lda,
    const unsigned short* __restrict__ B1g, const unsigned short* __restrict__ B2g,
    const unsigned short* __restrict__ B3g, int ldb,
    int K, int m0, int n0, char* lds, f32x4 acc[2][2])
{
    const int tid  = threadIdx.x;
    const int wave = tid >> 6, lane = tid & 63;
    const int wr = wave >> 2, wc = wave & 3;       // 2 x 4 wave grid, 32x32 each
    const int g = lane >> 4, r16 = lane & 15;

    int aoff[2], boff[2];
    #pragma unroll
    for (int i = 0; i < 2; i++) {
        int ra = wr*32 + i*16 + r16;               // [0,64)
        aoff[i] = ra*64 + ((g ^ ((ra>>1)&3)) << 4);
    }
    #pragma unroll
    for (int j = 0; j < 2; j++) {
        int rb = wc*32 + j*16 + r16;               // [0,128)
        boff[j] = rb*64 + ((g ^ ((rb>>1)&3)) << 4);
    }
    // staging chunk for this thread: c = tid
    const int row0 = tid >> 2;                     // A: [0,64) for tid<256; B: [0,128)
    const int kg0  = ((tid & 3) ^ ((row0 >> 1) & 3)) * 8;
    const bool doA = (tid < 256);                  // wave-uniform
    char* dA = lds + wave*1024;                    // waves 0-3 -> [0,4K)
    char* dB = lds + 12288 + wave*1024;            // waves 0-7 -> [0,8K)

#define STAGE(kc, bo) do {                                                 \
        size_t gb_ = (size_t)(n0+row0)*ldb + (kc) + kg0;                   \
        if (doA) {                                                         \
            size_t ga_ = (size_t)(m0+row0)*lda + (kc) + kg0;               \
            gld_lds16(A1g + ga_, dA + (bo));                               \
            gld_lds16(A2g + ga_, dA + 4096 + (bo));                        \
            gld_lds16(A3g + ga_, dA + 8192 + (bo));                        \
        }                                                                  \
        gld_lds16(B1g + gb_, dB + (bo));                                   \
        gld_lds16(B2g + gb_, dB + 8192 + (bo));                            \
        gld_lds16(B3g + gb_, dB + 16384 + (bo));                           \
    } while (0)

    auto compute = [&](int bo) {
        bf16x8 a1[2], a2[2], a3[2], b1[2], b2[2], b3[2];
        #pragma unroll
        for (int i = 0; i < 2; i++) {
            a1[i] = *(const bf16x8*)(lds + bo +         aoff[i]);
            a2[i] = *(const bf16x8*)(lds + bo +  4096 + aoff[i]);
            a3[i] = *(const bf16x8*)(lds + bo +  8192 + aoff[i]);
        }
        #pragma unroll
        for (int j = 0; j < 2; j++) {
            b1[j] = *(const bf16x8*)(lds + bo + 12288 + boff[j]);
            b2[j] = *(const bf16x8*)(lds + bo + 20480 + boff[j]);
            b3[j] = *(const bf16x8*)(lds + bo + 28672 + boff[j]);
        }
        #pragma unroll
        for (int i = 0; i < 2; i++)
            #pragma unroll
            for (int j = 0; j < 2; j++) {
                acc[i][j] = __builtin_amdgcn_mfma_f32_16x16x32_bf16(a3[i], b1[j], acc[i][j], 0, 0, 0);
                acc[i][j] = __builtin_amdgcn_mfma_f32_16x16x32_bf16(a2[i], b2[j], acc[i][j], 0, 0, 0);
                acc[i][j] = __builtin_amdgcn_mfma_f32_16x16x32_bf16(a1[i], b3[j], acc[i][j], 0, 0, 0);
                acc[i][j] = __builtin_amdgcn_mfma_f32_16x16x32_bf16(a2[i], b1[j], acc[i][j], 0, 0, 0);
                acc[i][j] = __builtin_amdgcn_mfma_f32_16x16x32_bf16(a1[i], b2[j], acc[i][j], 0, 0, 0);
                acc[i][j] = __builtin_amdgcn_mfma_f32_16x16x32_bf16(a1[i], b1[j], acc[i][j], 0, 0, 0);
            }
    };

    const int NT = K / 32;
    STAGE(0, 0);
    int bo = 0;
    for (int t = 0; t < NT - 1; ++t) {
        STAGE((t+1)*32, bo ^ 36864);                       // prefetch next
        if (doA) asm volatile("s_waitcnt vmcnt(6)" ::: "memory");
        else     asm volatile("s_waitcnt vmcnt(3)" ::: "memory");
        __builtin_amdgcn_s_barrier();
        asm volatile("" ::: "memory");
        compute(bo);
        asm volatile("" ::: "memory");
        __builtin_amdgcn_s_barrier();                      // before overwrite
        bo ^= 36864;
    }
    asm volatile("s_waitcnt vmcnt(0)" ::: "memory");
    __builtin_amdgcn_s_barrier();
    asm volatile("" ::: "memory");
    compute(bo);
#undef STAGE
}

// ---------------- query GEMM: 64x128 tiles ----------------
__global__ __launch_bounds__(512, 4) void qgemm_kernel(
    const unsigned short* __restrict__ y1, const unsigned short* __restrict__ y2,
    const unsigned short* __restrict__ y3,
    const unsigned short* __restrict__ w1, const unsigned short* __restrict__ w2,
    const unsigned short* __restrict__ w3,
    const float* __restrict__ bias,
    unsigned short* __restrict__ q1, unsigned short* __restrict__ q2,
    unsigned short* __restrict__ q3)
{
    __shared__ char lds[73728];
    int m0 = blockIdx.y * 64, n0 = blockIdx.x * 128;
    f32x4 acc[2][2];
    #pragma unroll
    for (int i = 0; i < 2; i++)
        #pragma unroll
        for (int j = 0; j < 2; j++) acc[i][j] = (f32x4)0.f;
    mfma_gemm_tile(y1, y2, y3, Cc, w1, w2, w3, Cc, Cc, m0, n0, lds, acc);

    const int lane = threadIdx.x & 63, wave = threadIdx.x >> 6;
    const int wr = wave >> 2, wc = wave & 3;
    const int g = lane >> 4, r16 = lane & 15;
    #pragma unroll
    for (int i = 0; i < 2; i++)
        #pragma unroll
        for (int j = 0; j < 2; j++)
            #pragma unroll
            for (int reg = 0; reg < 4; reg++) {
                int m = m0 + wr*32 + i*16 + g*4 + reg;
                int n = n0 + wc*32 + j*16 + r16;
                float v = acc[i][j][reg] + bias[n];
                size_t o = (size_t)m * QDc + n;
                splitbf3(v, &q1[o], &q2[o], &q3[o]);
            }
}

// ---------------- score GEMM: per (b,h) 2048x640x256, 64x128 tiles ----------------
__global__ __launch_bounds__(512, 4) void sgemm_kernel(
    const unsigned short* __restrict__ q1, const unsigned short* __restrict__ q2,
    const unsigned short* __restrict__ q3,
    const unsigned short* __restrict__ k1, const unsigned short* __restrict__ k2,
    const unsigned short* __restrict__ k3,
    float* __restrict__ Ctmp)
{
    __shared__ char lds[73728];
    int b4h = blockIdx.z;
    size_t qo = (size_t)b4h * (Tc * KD2c);
    size_t ko = (size_t)(b4h & 3) * (NKEYS * KD2c);
    int m0 = blockIdx.y * 64, n0 = blockIdx.x * 128;
    f32x4 acc[2][2];
    #pragma unroll
    for (int i = 0; i < 2; i++)
        #pragma unroll
        for (int j = 0; j < 2; j++) acc[i][j] = (f32x4)0.f;
    mfma_gemm_tile(q1+qo, q2+qo, q3+qo, KD2c, k1+ko, k2+ko, k3+ko, KD2c,
                   KD2c, m0, n0, lds, acc);

    const int lane = threadIdx.x & 63, wave = threadIdx.x >> 6;
    const int wr = wave >> 2, wc = wave & 3;
    const int g = lane >> 4, r16 = lane & 15;
    float* Cb = Ctmp + (size_t)b4h * Tc * NKEYS;
    #pragma unroll
    for (int i = 0; i < 2; i++)
        #pragma unroll
        for (int j = 0; j < 2; j++)
            #pragma unroll
            for (int reg = 0; reg < 4; reg++) {
                int m = m0 + wr*32 + i*16 + g*4 + reg;
                int n = n0 + wc*32 + j*16 + r16;
                Cb[(size_t)m * NKEYS + n] = acc[i][j][reg];
            }
}

// ---------------- col max/argmax + s = score + cmax ----------------
__global__ __launch_bounds__(256) void colmax_kernel(
    const float* __restrict__ Ctmp, float* __restrict__ s, int* __restrict__ cidx)
{
    int rid = blockIdx.x * 4 + (threadIdx.x >> 6);
    int lane = threadIdx.x & 63;
    const float* row = Ctmp + (size_t)rid * NKEYS;
    float best = -3.4e38f; int bi = 0;
    #pragma unroll
    for (int i = 0; i < 8; i++) {
        int c = lane + i*64;                 // ascending c per lane
        float v = row[BLKc + c];
        if (v > best) { best = v; bi = c; }  // strict > keeps lowest c
    }
    #pragma unroll
    for (int off = 32; off > 0; off >>= 1) {
        float ov = __shfl_xor(best, off, 64);
        int   oi = __shfl_xor(bi,   off, 64);
        if (ov > best || (ov == best && oi < bi)) { best = ov; bi = oi; }
    }
    if (lane == 0) cidx[rid] = bi;
    #pragma unroll
    for (int e = lane; e < BLKc; e += 64)
        s[(size_t)rid*BLKc + e] = row[e] + best;
}

// ---------------- wave-per-row register-resident top-256 of 2048 ----------------
// also counts entries per destination bin (fused count_kernel)
__global__ __launch_bounds__(256) void topk_kernel(
    const float* __restrict__ s, const int* __restrict__ cidx,
    int* __restrict__ tk_j, int* __restrict__ tk_vidx, float* __restrict__ tk_score,
    int* __restrict__ counts)
{
    int wid  = (blockIdx.x << 2) + (threadIdx.x >> 6);  // row 0..1023
    int lane = threadIdx.x & 63;
    int batch = wid >> 7;          // b*4+h
    int i = wid & 127;
    const float* srow = s + (size_t)batch * (Tc*BLKc) + (size_t)i * 2048;
    int* bcounts = counts + (wid >> 9) * Tc;            // per-b counts

    unsigned key[8][4];
    #pragma unroll
    for (int r = 0; r < 8; r++) {
        float4 v4 = *(const float4*)&srow[r*256 + lane*4];
        float vv[4] = {v4.x, v4.y, v4.z, v4.w};
        #pragma unroll
        for (int e = 0; e < 4; e++) {
            unsigned u = __float_as_uint(vv[e]);
            key[r][e] = (u >> 31) ? ~u : (u | 0x80000000u);   // order-preserving
        }
    }

    // binary search: largest thr with count(key >= thr) >= 256
    unsigned lo = 0, hi = 0xFFFFFFFFu;
    while (lo < hi) {
        unsigned d = hi - lo;
        unsigned mid = lo + ((d >> 1) + (d & 1u));
        int cnt = 0;
        #pragma unroll
        for (int r = 0; r < 8; r++)
            #pragma unroll
            for (int e = 0; e < 4; e++)
                cnt += (key[r][e] >= mid) ? 1 : 0;
        #pragma unroll
        for (int off = 32; off > 0; off >>= 1) cnt += __shfl_xor(cnt, off, 64);
        if (cnt >= KSELc) lo = mid; else hi = mid - 1;
    }
    const unsigned thr = lo;

    // per-lane greater count + eq bitmask
    int gcnt = 0, ecnt = 0;
    unsigned eqmask = 0;
    #pragma unroll
    for (int r = 0; r < 8; r++)
        #pragma unroll
        for (int e = 0; e < 4; e++) {
            gcnt += (key[r][e] > thr) ? 1 : 0;
            if (key[r][e] == thr) { eqmask |= (1u << (r*4+e)); ecnt++; }
        }

    // exclusive scans across lanes
    int gpre = gcnt, epre = ecnt;
    #pragma unroll
    for (int off = 1; off < 64; off <<= 1) {
        int gv = __shfl_up(gpre, off, 64);
        int ev = __shfl_up(epre, off, 64);
        if (lane >= off) { gpre += gv; epre += ev; }
    }
    const int total_greater = __shfl(gpre, 63, 64);
    const int total_eq      = __shfl(epre, 63, 64);
    const int gbase = gpre - gcnt;
    const int ebase = epre - ecnt;
    const int need  = KSELc - total_greater;   // >= 1

    const size_t obase = (size_t)wid * KSELc;
    const int cbase = batch * Tc + i * 16;

    // emit strictly-greater (any order)
    int rk = 0;
    #pragma unroll
    for (int r = 0; r < 8; r++)
        #pragma unroll
        for (int e = 0; e < 4; e++) {
            if (key[r][e] > thr) {
                int j = r*256 + lane*4 + e;
                unsigned u = key[r][e];
                float f = (u >> 31) ? __uint_as_float(u ^ 0x80000000u)
                                    : __uint_as_float(~u);
                size_t o = obase + gbase + rk;
                tk_j[o] = j;
                tk_vidx[o] = (j & 127) * COLc + cidx[cbase + (j >> 7)];
                tk_score[o] = f;
                atomicAdd(&bcounts[j], 1);
                rk++;
            }
        }

    if (need == total_eq) {
        int erk = 0;
        #pragma unroll
        for (int r = 0; r < 8; r++)
            #pragma unroll
            for (int e = 0; e < 4; e++) {
                if (key[r][e] == thr) {
                    int j = r*256 + lane*4 + e;
                    float f = (thr >> 31) ? __uint_as_float(thr ^ 0x80000000u)
                                          : __uint_as_float(~thr);
                    size_t o = obase + total_greater + ebase + erk;
                    tk_j[o] = j;
                    tk_vidx[o] = (j & 127) * COLc + cidx[cbase + (j >> 7)];
                    tk_score[o] = f;
                    atomicAdd(&bcounts[j], 1);
                    erk++;
                }
            }
    } else {
        // rare: duplicate keys at threshold — lowest-j first, serially
        unsigned em = eqmask;
        int left = need;
        while (left > 0) {
            int myj = 0x7FFFFFFF;
            if (em) {
                int bit = __builtin_ctz(em);
                myj = (bit >> 2)*256 + lane*4 + (bit & 3);
            }
            int mn = myj;
            #pragma unroll
            for (int off = 32; off > 0; off >>= 1) mn = min(mn, __shfl_xor(mn, off, 64));
            if (myj == mn) {
                em &= em - 1;
                int j = mn;
                float f = (thr >> 31) ? __uint_as_float(thr ^ 0x80000000u)
                                      : __uint_as_float(~thr);
                size_t o = obase + (KSELc - left);
                tk_j[o] = j;
                tk_vidx[o] = (j & 127) * COLc + cidx[cbase + (j >> 7)];
                tk_score[o] = f;
                atomicAdd(&bcounts[j], 1);
            }
            left--;
        }
    }
}

// ---------------- zero helpers ----------------
__global__ __launch_bounds__(256) void zero_bins_kernel(int* __restrict__ p, int n)
{
    int i = blockIdx.x * 256 + threadIdx.x;
    if (i < n) p[i] = 0;
}

__global__ __launch_bounds__(256) void zero_out_kernel(float4* __restrict__ p, int n4)
{
    int i = blockIdx.x * 256 + threadIdx.x;
    if (i < n4) p[i] = float4{0.f, 0.f, 0.f, 0.f};
}

// ---------------- scan + chunk emission (single block) ----------------
__global__ __launch_bounds__(256) void scan_chunks_kernel(
    const int* __restrict__ counts, int* __restrict__ offsets,
    int* __restrict__ nchunks, int4* __restrict__ chunks)
{
    __shared__ int part[256];
    int tid = threadIdx.x;
    int local[16], ccnt[16];
    int sum = 0;
    #pragma unroll
    for (int k = 0; k < 16; k++) {
        ccnt[k] = counts[tid*16 + k];
        local[k] = sum; sum += ccnt[k];
    }
    part[tid] = sum;
    __syncthreads();
    for (int st = 1; st < 256; st <<= 1) {
        int v = (tid >= st) ? part[tid - st] : 0;
        __syncthreads();
        part[tid] += v;
        __syncthreads();
    }
    int base = (tid == 0) ? 0 : part[tid - 1];
    #pragma unroll
    for (int k = 0; k < 16; k++) offsets[tid*16 + k] = base + local[k];
    if (tid == 255) offsets[NBINS] = base + sum;

    // emit chunk descriptors (<=64 entries each)
    #pragma unroll
    for (int k = 0; k < 16; k++) {
        int cnt = ccnt[k];
        if (cnt <= 0) continue;
        int beg = base + local[k];
        int nch = (cnt + 63) >> 6;
        int cb = atomicAdd(nchunks, nch);
        for (int kk = 0; kk < nch; kk++) {
            int s0 = beg + kk*64;
            int s1 = min(beg + cnt, s0 + 64);
            chunks[cb + kk] = make_int4(tid*16 + k, s0, s1, (nch > 1) ? 1 : 0);
        }
    }
}

__global__ __launch_bounds__(256) void fill_kernel(
    const int* __restrict__ tk_j, const int* __restrict__ tk_vidx,
    const float* __restrict__ tk_score, const int* __restrict__ offsets,
    int* __restrict__ fillctr, int* __restrict__ bin_vidx,
    float* __restrict__ bin_score)
{
    int idx = blockIdx.x * 256 + threadIdx.x;
    int r = idx >> 8;
    int b = r >> 9;
    int bin = b * Tc + tk_j[idx];
    int pos = offsets[bin] + atomicAdd(&fillctr[bin], 1);
    bin_vidx[pos]  = tk_vidx[idx];
    bin_score[pos] = tk_score[idx];
}

// ---------------- gather: chunked, load-balanced, float4 lanes ----------------
__global__ __launch_bounds__(128) void gather_kernel(
    const int* __restrict__ nchunks, const int4* __restrict__ chunks,
    const int* __restrict__ bin_vidx, const float* __restrict__ bin_score,
    const float* __restrict__ value_w, float* __restrict__ out)
{
    if ((int)blockIdx.x >= *nchunks) return;
    int4 ch = chunks[blockIdx.x];
    const int bin = ch.x, beg = ch.y, cnt = ch.z - ch.y, multi = ch.w;
    const int tid = threadIdx.x;

    __shared__ int   svidx[64];
    __shared__ float sscore[64];
    if (tid < cnt) { svidx[tid] = bin_vidx[beg + tid]; sscore[tid] = bin_score[beg + tid]; }
    __syncthreads();

    const int c = tid * 4;
    float4 acc = {0.f, 0.f, 0.f, 0.f};
    int n = 0;
    for (; n + 8 <= cnt; n += 8) {
        int vi[8]; float sc[8]; float4 vv[8];
        #pragma unroll
        for (int k = 0; k < 8; k++) { vi[k] = svidx[n+k]; sc[k] = sscore[n+k]; }
        #pragma unroll
        for (int k = 0; k < 8; k++)
            vv[k] = *(const float4*)&value_w[(size_t)vi[k] * DOUTc + c];
        #pragma unroll
        for (int k = 0; k < 8; k++) {
            acc.x += sc[k]*vv[k].x; acc.y += sc[k]*vv[k].y;
            acc.z += sc[k]*vv[k].z; acc.w += sc[k]*vv[k].w;
        }
    }
    for (; n < cnt; n++) {
        int v = svidx[n]; float sc = sscore[n];
        float4 a = *(const float4*)&value_w[(size_t)v * DOUTc + c];
        acc.x += sc*a.x; acc.y += sc*a.y; acc.z += sc*a.z; acc.w += sc*a.w;
    }
    float* orow = out + (size_t)bin * DOUTc + c;
    if (multi) {
        atomicAdd(&orow[0], acc.x);
        atomicAdd(&orow[1], acc.y);
        atomicAdd(&orow[2], acc.z);
        atomicAdd(&orow[3], acc.w);
    } else {
        *(float4*)orow = acc;
    }
}

// ---------------- launch ----------------
extern "C" void kernel_launch(void* const* d_in, const int* in_sizes, int n_in,
                              void* d_out, int out_size, void* d_ws, size_t ws_size,
                              hipStream_t stream)
{
    const float* x       = (const float*)d_in[0];
    const float* conv_w  = (const float*)d_in[1];
    const float* conv_b  = (const float*)d_in[2];
    const float* lin_w   = (const float*)d_in[3];
    const float* lin_b   = (const float*)d_in[4];
    const float* rowkeys = (const float*)d_in[5];
    const float* colkeys = (const float*)d_in[6];
    const float* value_w = (const float*)d_in[7];
    float* out = (float*)d_out;

    constexpr size_t MB = 1024*1024;
    char* w = (char*)d_ws;
    // Ctmp [0,40MB) overlays y1/y2/y3/w1/w2/w3 (dead after qgemm)
    float*          Ctmp = (float*)(w);                  // 40 MB @ 0
    unsigned short* y1   = (unsigned short*)(w);         //  8 MB @ 0
    unsigned short* y2   = (unsigned short*)(w +  8*MB); //  8 MB
    unsigned short* y3   = (unsigned short*)(w + 16*MB); //  8 MB
    unsigned short* w1   = (unsigned short*)(w + 24*MB); //  2 MB
    unsigned short* w2   = (unsigned short*)(w + 26*MB); //  2 MB
    unsigned short* w3   = (unsigned short*)(w + 28*MB); //  2 MB
    unsigned short* q1   = (unsigned short*)(w + 40*MB); //  8 MB
    unsigned short* q2   = (unsigned short*)(w + 48*MB); //  8 MB
    unsigned short* q3   = (unsigned short*)(w + 56*MB); //  8 MB
    unsigned short* k1   = (unsigned short*)(w + 64*MB); //  1.25 MB
    unsigned short* k2   = (unsigned short*)(w + 66*MB); //  1.25 MB
    unsigned short* k3   = (unsigned short*)(w + 68*MB); //  1.25 MB
    float*          s    = (float*)(w + 70*MB);          //  8 MB
    int*            cidx = (int*)  (w + 78*MB);          //  64 KB
    int*            tk_j = (int*)  (w + 79*MB);          //  1 MB
    int*            tk_v = (int*)  (w + 80*MB);          //  1 MB
    float*          tk_s = (float*)(w + 81*MB);          //  1 MB
    int*            counts    = (int*)  (w + 82*MB);               // 16 KB
    int*            offsets   = (int*)  (w + 82*MB + 32768);       // 16 KB + 4
    int*            fillctr   = (int*)  (w + 82*MB + 65536);       // 16 KB
    int*            nchunks   = (int*)  (w + 82*MB + 81920);       // 4 B (zeroed region)
    int*            bin_vidx  = (int*)  (w + 82*MB + 131072);      // 1 MB
    float*          bin_score = (float*)(w + 82*MB + 131072 + 1048576); // 1 MB
    int4*           chunks    = (int4*) (w + 82*MB + 131072 + 2097152); // 128 KB

    // 0. zero counts/offsets/fillctr/nchunks + out (counting is fused into topk)
    zero_bins_kernel<<<(96*1024/4 + 255)/256, 256, 0, stream>>>(counts, 96*1024/4);
    zero_out_kernel<<<(out_size/4 + 255)/256, 256, 0, stream>>>((float4*)out, out_size/4);
    // 1. conv -> y h/m/l
    conv_kernel<<<(Bc*Tc*Cc)/256, 256, 0, stream>>>(x, conv_w, conv_b, y1, y2, y3);
    // 2. convert lin_w, keys
    convw_kernel<<<(QDc*Cc)/256, 256, 0, stream>>>(lin_w, w1, w2, w3);
    convkeys_kernel<<<Hc*NKEYS, 256, 0, stream>>>(rowkeys, colkeys, k1, k2, k3);
    // 3. query GEMM -> q h/m/l (64x128 tiles, 512 blocks)
    qgemm_kernel<<<dim3(QDc/128, (Bc*Tc)/64), 512, 0, stream>>>(
        y1, y2, y3, w1, w2, w3, lin_b, q1, q2, q3);
    // 4. score GEMM -> Ctmp (64x128 tiles, 1280 blocks)
    sgemm_kernel<<<dim3(NKEYS/128, Tc/64, Bc*Hc), 512, 0, stream>>>(
        q1, q2, q3, k1, k2, k3, Ctmp);
    // 5. col max + s
    colmax_kernel<<<(Bc*Hc*Tc)/4, 256, 0, stream>>>(Ctmp, s, cidx);
    // 6. topk (wave-per-row, register-resident, fused bin counting)
    topk_kernel<<<Bc*Hc*BLKc/4, 256, 0, stream>>>(s, cidx, tk_j, tk_v, tk_s, counts);
    // 7. scan + chunk emission, then fill
    scan_chunks_kernel<<<1, 256, 0, stream>>>(counts, offsets, nchunks, chunks);
    fill_kernel<<<NSEL/256, 256, 0, stream>>>(tk_j, tk_v, tk_s, offsets,
                                              fillctr, bin_vidx, bin_score);
    // 8. gather (load-balanced chunks)
    gather_kernel<<<MAXCHUNKS, 128, 0, stream>>>(nchunks, chunks, bin_vidx,
                                                 bin_score, value_w, out);
}

// Round 11
// 223.007 us; speedup vs baseline: 1.4629x; 1.4629x over previous
//
#include <hip/hip_runtime.h>

// ---------------- problem constants ----------------
constexpr int Bc   = 2;
constexpr int Tc   = 2048;
constexpr int Cc   = 1024;   // D_IN
constexpr int QDc  = 1024;   // query dim
constexpr int Hc   = 4;
constexpr int KD2c = 256;
constexpr int BLKc = 128;    // BLOCK (row keys)
constexpr int COLc = 512;    // col keys
constexpr int DOUTc= 512;
constexpr int KSELc= 256;    // top-k per row
constexpr int NKEYS= BLKc + COLc; // 640
constexpr int NBINS= Bc * Tc;     // 4096
constexpr int NSEL = Bc * Hc * BLKc * KSELc; // 262144

typedef short bf16x8 __attribute__((ext_vector_type(8)));
typedef float f32x4  __attribute__((ext_vector_type(4)));

// ---------------- bf16 3-way split helpers ----------------
__device__ __forceinline__ unsigned short f2bf(float f) {
    unsigned u = __float_as_uint(f);
    u += 0x7FFFu + ((u >> 16) & 1u);        // round-to-nearest-even
    return (unsigned short)(u >> 16);
}
__device__ __forceinline__ float bf2f(unsigned short h) {
    return __uint_as_float((unsigned)h << 16);
}
// f ~= h + m + l  (each bf16; residual ~2^-27 relative)
__device__ __forceinline__ void splitbf3(float f, unsigned short* h,
                                         unsigned short* m, unsigned short* l) {
    unsigned short hh = f2bf(f);
    float r1 = f - bf2f(hh);
    unsigned short mm = f2bf(r1);
    float r2 = r1 - bf2f(mm);
    *h = hh; *m = mm; *l = f2bf(r2);
}

__device__ __forceinline__ void gld_lds16(const void* g, void* l) {
    __builtin_amdgcn_global_load_lds(
        (const __attribute__((address_space(1))) unsigned int*)g,
        (__attribute__((address_space(3))) unsigned int*)l, 16, 0, 0);
}

// ---------------- conv: causal depthwise k=3, bf16 h/m/l output ----------------
__global__ __launch_bounds__(256) void conv_kernel(
    const float* __restrict__ x, const float* __restrict__ cw,
    const float* __restrict__ cb, unsigned short* __restrict__ y1,
    unsigned short* __restrict__ y2, unsigned short* __restrict__ y3)
{
    int idx = blockIdx.x * 256 + threadIdx.x;       // over B*T*C = 2^22
    int c = idx & (Cc - 1);
    int t = (idx >> 10) & (Tc - 1);
    int b = idx >> 21;
    float w0 = cw[c*3+0], w1 = cw[c*3+1], w2 = cw[c*3+2];
    const float* xb = x + (size_t)b * Tc * Cc;
    float acc = cb[c] + w2 * xb[(size_t)t*Cc + c];
    if (t >= 1) acc += w1 * xb[(size_t)(t-1)*Cc + c];
    if (t >= 2) acc += w0 * xb[(size_t)(t-2)*Cc + c];
    splitbf3(acc, &y1[idx], &y2[idx], &y3[idx]);
}

// ---------------- convert lin_w to h/m/l bf16 ----------------
__global__ __launch_bounds__(256) void convw_kernel(
    const float* __restrict__ w, unsigned short* __restrict__ w1,
    unsigned short* __restrict__ w2, unsigned short* __restrict__ w3)
{
    int idx = blockIdx.x * 256 + threadIdx.x;   // 1M elems
    splitbf3(w[idx], &w1[idx], &w2[idx], &w3[idx]);
}

// ---------------- convert keys to [h][640][256] h/m/l bf16 ----------------
__global__ __launch_bounds__(256) void convkeys_kernel(
    const float* __restrict__ rowkeys, const float* __restrict__ colkeys,
    unsigned short* __restrict__ k1, unsigned short* __restrict__ k2,
    unsigned short* __restrict__ k3)
{
    int bid = blockIdx.x;          // 0..2559 : h*640+n
    int h = bid / NKEYS, n = bid % NKEYS;
    int k = threadIdx.x;           // 0..255
    float v = (n < BLKc) ? rowkeys[((size_t)n*Hc + h)*KD2c + k]
                         : colkeys[((size_t)(n-BLKc)*Hc + h)*KD2c + k];
    size_t o = ((size_t)h*NKEYS + n)*KD2c + k;
    splitbf3(v, &k1[o], &k2[o], &k3[o]);
}

// ---------------- split-bf16(x3) MFMA GEMM core, 8 waves, double-buffered ----
// 128x128 tile, 8 waves (wave-tile 64x32: WARPS_M=2 x WARPS_N=4), K-step 32.
// LDS: two 48KB buffers (A1 0,A2 8K,A3 16K,B1 24K,B2 32K,B3 40K within each).
// swizzle: chunk (row, slot) holds k-group (slot ^ ((row>>1)&3)).
// Each of 512 threads stages ONE 16B chunk per array (6 gld_lds16) -> vmcnt(6).
__device__ __forceinline__ void mfma_gemm_tile(
    const unsigned short* __restrict__ A1g, const unsigned short* __restrict__ A2g,
    const unsigned short* __restrict__ A3g, int lda,
    const unsigned short* __restrict__ B1g, const unsigned short* __restrict__ B2g,
    const unsigned short* __restrict__ B3g, int ldb,
    int K, int m0, int n0, char* lds, f32x4 acc[4][2])
{
    const int tid  = threadIdx.x;
    const int wave = tid >> 6, lane = tid & 63;
    const int wr = wave >> 2, wc = wave & 3;       // 2 x 4 wave grid
    const int g = lane >> 4, r16 = lane & 15;

    int aoff[4], boff[2];
    #pragma unroll
    for (int i = 0; i < 4; i++) {
        int ra = wr*64 + i*16 + r16;
        aoff[i] = ra*64 + ((g ^ ((ra>>1)&3)) << 4);
    }
    #pragma unroll
    for (int j = 0; j < 2; j++) {
        int rb = wc*32 + j*16 + r16;
        boff[j] = rb*64 + ((g ^ ((rb>>1)&3)) << 4);
    }
    const int row0 = tid >> 2, kg0 = ((tid & 3) ^ ((row0>>1)&3)) * 8;
    char* d0 = lds + wave*1024;

#define STAGE(kc, bo) do {                                                 \
        size_t a0_ = (size_t)(m0+row0)*lda + (kc) + kg0;                   \
        size_t b0_ = (size_t)(n0+row0)*ldb + (kc) + kg0;                   \
        gld_lds16(A1g + a0_, d0 + (bo));                                   \
        gld_lds16(A2g + a0_, d0 + 8192 + (bo));                            \
        gld_lds16(A3g + a0_, d0 + 16384 + (bo));                           \
        gld_lds16(B1g + b0_, d0 + 24576 + (bo));                           \
        gld_lds16(B2g + b0_, d0 + 32768 + (bo));                           \
        gld_lds16(B3g + b0_, d0 + 40960 + (bo));                           \
    } while (0)

    auto compute = [&](int bo) {
        bf16x8 a1[4], a2[4], a3[4], b1[2], b2[2], b3[2];
        #pragma unroll
        for (int i = 0; i < 4; i++) {
            a1[i] = *(const bf16x8*)(lds + bo + aoff[i]);
            a2[i] = *(const bf16x8*)(lds + bo +  8192 + aoff[i]);
            a3[i] = *(const bf16x8*)(lds + bo + 16384 + aoff[i]);
        }
        #pragma unroll
        for (int j = 0; j < 2; j++) {
            b1[j] = *(const bf16x8*)(lds + bo + 24576 + boff[j]);
            b2[j] = *(const bf16x8*)(lds + bo + 32768 + boff[j]);
            b3[j] = *(const bf16x8*)(lds + bo + 40960 + boff[j]);
        }
        #pragma unroll
        for (int i = 0; i < 4; i++)
            #pragma unroll
            for (int j = 0; j < 2; j++) {
                acc[i][j] = __builtin_amdgcn_mfma_f32_16x16x32_bf16(a3[i], b1[j], acc[i][j], 0, 0, 0);
                acc[i][j] = __builtin_amdgcn_mfma_f32_16x16x32_bf16(a2[i], b2[j], acc[i][j], 0, 0, 0);
                acc[i][j] = __builtin_amdgcn_mfma_f32_16x16x32_bf16(a1[i], b3[j], acc[i][j], 0, 0, 0);
                acc[i][j] = __builtin_amdgcn_mfma_f32_16x16x32_bf16(a2[i], b1[j], acc[i][j], 0, 0, 0);
                acc[i][j] = __builtin_amdgcn_mfma_f32_16x16x32_bf16(a1[i], b2[j], acc[i][j], 0, 0, 0);
                acc[i][j] = __builtin_amdgcn_mfma_f32_16x16x32_bf16(a1[i], b1[j], acc[i][j], 0, 0, 0);
            }
    };

    const int NT = K / 32;
    STAGE(0, 0);
    int bo = 0;
    for (int t = 0; t < NT - 1; ++t) {
        STAGE((t+1)*32, bo ^ 49152);                       // prefetch next
        asm volatile("s_waitcnt vmcnt(6)" ::: "memory");   // wait current only
        __builtin_amdgcn_s_barrier();
        asm volatile("" ::: "memory");
        compute(bo);
        asm volatile("" ::: "memory");
        __builtin_amdgcn_s_barrier();                      // before overwrite
        bo ^= 49152;
    }
    asm volatile("s_waitcnt vmcnt(0)" ::: "memory");
    __builtin_amdgcn_s_barrier();
    asm volatile("" ::: "memory");
    compute(bo);
#undef STAGE
}

// ---------------- query GEMM (flat grid, XCD-swizzled) ----------------
// 256 blocks; XCD k owns M-rows {4k..4k+3} x all N -> A panels L2-resident.
__global__ __launch_bounds__(512) void qgemm_kernel(
    const unsigned short* __restrict__ y1, const unsigned short* __restrict__ y2,
    const unsigned short* __restrict__ y3,
    const unsigned short* __restrict__ w1, const unsigned short* __restrict__ w2,
    const unsigned short* __restrict__ w3,
    const float* __restrict__ bias,
    unsigned short* __restrict__ q1, unsigned short* __restrict__ q2,
    unsigned short* __restrict__ q3)
{
    __shared__ char lds[98304];
    int l = blockIdx.x;                          // [0,256)
    int yb = (l & 7) * 4 + ((l >> 3) & 3);       // M-tile [0,32)
    int xb = l >> 5;                             // N-tile [0,8)
    int m0 = yb * 128, n0 = xb * 128;
    f32x4 acc[4][2];
    #pragma unroll
    for (int i = 0; i < 4; i++)
        #pragma unroll
        for (int j = 0; j < 2; j++) acc[i][j] = (f32x4)0.f;
    mfma_gemm_tile(y1, y2, y3, Cc, w1, w2, w3, Cc, Cc, m0, n0, lds, acc);

    const int lane = threadIdx.x & 63, wave = threadIdx.x >> 6;
    const int wr = wave >> 2, wc = wave & 3;
    const int g = lane >> 4, r16 = lane & 15;
    #pragma unroll
    for (int i = 0; i < 4; i++)
        #pragma unroll
        for (int j = 0; j < 2; j++)
            #pragma unroll
            for (int reg = 0; reg < 4; reg++) {
                int m = m0 + wr*64 + i*16 + g*4 + reg;
                int n = n0 + wc*32 + j*16 + r16;
                float v = acc[i][j][reg] + bias[n];
                size_t o = (size_t)m * QDc + n;
                splitbf3(v, &q1[o], &q2[o], &q3[o]);
            }
}

// ---------------- score GEMM (flat grid, XCD-swizzled) ----------------
// 640 blocks; XCD k owns (b,h)=k entirely (q panel + keys ~= one L2).
__global__ __launch_bounds__(512) void sgemm_kernel(
    const unsigned short* __restrict__ q1, const unsigned short* __restrict__ q2,
    const unsigned short* __restrict__ q3,
    const unsigned short* __restrict__ k1, const unsigned short* __restrict__ k2,
    const unsigned short* __restrict__ k3,
    float* __restrict__ Ctmp)
{
    __shared__ char lds[98304];
    int l = blockIdx.x;                          // [0,640)
    int b4h = l & 7;                             // (b,h) == XCD
    int m5  = l >> 3;                            // [0,80)
    int xb  = m5 % 5;                            // N-tile [0,5)
    int yb  = m5 / 5;                            // M-tile [0,16)
    size_t qo = (size_t)b4h * (Tc * KD2c);
    size_t ko = (size_t)(b4h & 3) * (NKEYS * KD2c);
    int m0 = yb * 128, n0 = xb * 128;
    f32x4 acc[4][2];
    #pragma unroll
    for (int i = 0; i < 4; i++)
        #pragma unroll
        for (int j = 0; j < 2; j++) acc[i][j] = (f32x4)0.f;
    mfma_gemm_tile(q1+qo, q2+qo, q3+qo, KD2c, k1+ko, k2+ko, k3+ko, KD2c,
                   KD2c, m0, n0, lds, acc);

    const int lane = threadIdx.x & 63, wave = threadIdx.x >> 6;
    const int wr = wave >> 2, wc = wave & 3;
    const int g = lane >> 4, r16 = lane & 15;
    float* Cb = Ctmp + (size_t)b4h * Tc * NKEYS;
    #pragma unroll
    for (int i = 0; i < 4; i++)
        #pragma unroll
        for (int j = 0; j < 2; j++)
            #pragma unroll
            for (int reg = 0; reg < 4; reg++) {
                int m = m0 + wr*64 + i*16 + g*4 + reg;
                int n = n0 + wc*32 + j*16 + r16;
                Cb[(size_t)m * NKEYS + n] = acc[i][j][reg];
            }
}

// ---------------- col max/argmax + s = score + cmax ----------------
__global__ __launch_bounds__(256) void colmax_kernel(
    const float* __restrict__ Ctmp, float* __restrict__ s, int* __restrict__ cidx)
{
    int rid = blockIdx.x * 4 + (threadIdx.x >> 6);
    int lane = threadIdx.x & 63;
    const float* row = Ctmp + (size_t)rid * NKEYS;
    float best = -3.4e38f; int bi = 0;
    #pragma unroll
    for (int i = 0; i < 8; i++) {
        int c = lane + i*64;                 // ascending c per lane
        float v = row[BLKc + c];
        if (v > best) { best = v; bi = c; }  // strict > keeps lowest c
    }
    #pragma unroll
    for (int off = 32; off > 0; off >>= 1) {
        float ov = __shfl_xor(best, off, 64);
        int   oi = __shfl_xor(bi,   off, 64);
        if (ov > best || (ov == best && oi < bi)) { best = ov; bi = oi; }
    }
    if (lane == 0) cidx[rid] = bi;
    #pragma unroll
    for (int e = lane; e < BLKc; e += 64)
        s[(size_t)rid*BLKc + e] = row[e] + best;
}

// ---------------- wave-per-row register-resident top-256 of 2048 ----------------
__global__ __launch_bounds__(256) void topk_kernel(
    const float* __restrict__ s, const int* __restrict__ cidx,
    int* __restrict__ tk_j, int* __restrict__ tk_vidx, float* __restrict__ tk_score)
{
    int wid  = (blockIdx.x << 2) + (threadIdx.x >> 6);  // row 0..1023
    int lane = threadIdx.x & 63;
    int batch = wid >> 7;          // b*4+h
    int i = wid & 127;
    const float* srow = s + (size_t)batch * (Tc*BLKc) + (size_t)i * 2048;

    unsigned key[8][4];
    #pragma unroll
    for (int r = 0; r < 8; r++) {
        float4 v4 = *(const float4*)&srow[r*256 + lane*4];
        float vv[4] = {v4.x, v4.y, v4.z, v4.w};
        #pragma unroll
        for (int e = 0; e < 4; e++) {
            unsigned u = __float_as_uint(vv[e]);
            key[r][e] = (u >> 31) ? ~u : (u | 0x80000000u);   // order-preserving
        }
    }

    // binary search: largest thr with count(key >= thr) >= 256
    unsigned lo = 0, hi = 0xFFFFFFFFu;
    while (lo < hi) {
        unsigned d = hi - lo;
        unsigned mid = lo + ((d >> 1) + (d & 1u));
        int cnt = 0;
        #pragma unroll
        for (int r = 0; r < 8; r++)
            #pragma unroll
            for (int e = 0; e < 4; e++)
                cnt += (key[r][e] >= mid) ? 1 : 0;
        #pragma unroll
        for (int off = 32; off > 0; off >>= 1) cnt += __shfl_xor(cnt, off, 64);
        if (cnt >= KSELc) lo = mid; else hi = mid - 1;
    }
    const unsigned thr = lo;

    // per-lane greater count + eq bitmask
    int gcnt = 0, ecnt = 0;
    unsigned eqmask = 0;
    #pragma unroll
    for (int r = 0; r < 8; r++)
        #pragma unroll
        for (int e = 0; e < 4; e++) {
            gcnt += (key[r][e] > thr) ? 1 : 0;
            if (key[r][e] == thr) { eqmask |= (1u << (r*4+e)); ecnt++; }
        }

    // exclusive scans across lanes
    int gpre = gcnt, epre = ecnt;
    #pragma unroll
    for (int off = 1; off < 64; off <<= 1) {
        int gv = __shfl_up(gpre, off, 64);
        int ev = __shfl_up(epre, off, 64);
        if (lane >= off) { gpre += gv; epre += ev; }
    }
    const int total_greater = __shfl(gpre, 63, 64);
    const int total_eq      = __shfl(epre, 63, 64);
    const int gbase = gpre - gcnt;
    const int ebase = epre - ecnt;
    const int need  = KSELc - total_greater;   // >= 1

    const size_t obase = (size_t)wid * KSELc;
    const int cbase = batch * Tc + i * 16;

    // emit strictly-greater (any order)
    int rk = 0;
    #pragma unroll
    for (int r = 0; r < 8; r++)
        #pragma unroll
        for (int e = 0; e < 4; e++) {
            if (key[r][e] > thr) {
                int j = r*256 + lane*4 + e;
                unsigned u = key[r][e];
                float f = (u >> 31) ? __uint_as_float(u ^ 0x80000000u)
                                    : __uint_as_float(~u);
                size_t o = obase + gbase + rk;
                tk_j[o] = j;
                tk_vidx[o] = (j & 127) * COLc + cidx[cbase + (j >> 7)];
                tk_score[o] = f;
                rk++;
            }
        }

    if (need == total_eq) {
        int erk = 0;
        #pragma unroll
        for (int r = 0; r < 8; r++)
            #pragma unroll
            for (int e = 0; e < 4; e++) {
                if (key[r][e] == thr) {
                    int j = r*256 + lane*4 + e;
                    float f = (thr >> 31) ? __uint_as_float(thr ^ 0x80000000u)
                                          : __uint_as_float(~thr);
                    size_t o = obase + total_greater + ebase + erk;
                    tk_j[o] = j;
                    tk_vidx[o] = (j & 127) * COLc + cidx[cbase + (j >> 7)];
                    tk_score[o] = f;
                    erk++;
                }
            }
    } else {
        // rare: duplicate keys at threshold — lowest-j first, serially
        unsigned em = eqmask;
        int left = need;
        while (left > 0) {
            int myj = 0x7FFFFFFF;
            if (em) {
                int bit = __builtin_ctz(em);
                myj = (bit >> 2)*256 + lane*4 + (bit & 3);
            }
            int mn = myj;
            #pragma unroll
            for (int off = 32; off > 0; off >>= 1) mn = min(mn, __shfl_xor(mn, off, 64));
            if (myj == mn) {
                em &= em - 1;
                int j = mn;
                float f = (thr >> 31) ? __uint_as_float(thr ^ 0x80000000u)
                                      : __uint_as_float(~thr);
                size_t o = obase + (KSELc - left);
                tk_j[o] = j;
                tk_vidx[o] = (j & 127) * COLc + cidx[cbase + (j >> 7)];
                tk_score[o] = f;
            }
            left--;
        }
    }
}

// ---------------- binning: zero / count / scan / fill ----------------
__global__ __launch_bounds__(256) void zero_bins_kernel(int* __restrict__ p, int n)
{
    int i = blockIdx.x * 256 + threadIdx.x;
    if (i < n) p[i] = 0;
}

__global__ __launch_bounds__(256) void count_kernel(
    const int* __restrict__ tk_j, int* __restrict__ counts)
{
    int idx = blockIdx.x * 256 + threadIdx.x;   // 0..NSEL-1
    int r = idx >> 8;                           // (b,h,i)
    int b = r >> 9;
    int j = tk_j[idx];
    atomicAdd(&counts[b * Tc + j], 1);
}

__global__ __launch_bounds__(256) void scan_kernel(
    const int* __restrict__ counts, int* __restrict__ offsets)
{
    __shared__ int part[256];
    int tid = threadIdx.x;
    int local[16];
    int sum = 0;
    #pragma unroll
    for (int k = 0; k < 16; k++) { local[k] = sum; sum += counts[tid*16 + k]; }
    part[tid] = sum;
    __syncthreads();
    for (int st = 1; st < 256; st <<= 1) {
        int v = (tid >= st) ? part[tid - st] : 0;
        __syncthreads();
        part[tid] += v;
        __syncthreads();
    }
    int base = (tid == 0) ? 0 : part[tid - 1];
    #pragma unroll
    for (int k = 0; k < 16; k++) offsets[tid*16 + k] = base + local[k];
    if (tid == 255) offsets[NBINS] = base + sum;
}

__global__ __launch_bounds__(256) void fill_kernel(
    const int* __restrict__ tk_j, const int* __restrict__ tk_vidx,
    const float* __restrict__ tk_score, const int* __restrict__ offsets,
    int* __restrict__ fillctr, int* __restrict__ bin_vidx,
    float* __restrict__ bin_score)
{
    int idx = blockIdx.x * 256 + threadIdx.x;
    int r = idx >> 8;
    int b = r >> 9;
    int bin = b * Tc + tk_j[idx];
    int pos = offsets[bin] + atomicAdd(&fillctr[bin], 1);
    bin_vidx[pos]  = tk_vidx[idx];
    bin_score[pos] = tk_score[idx];
}

// ---------------- gather: out[bin,:] = sum score * value_w[vidx,:] ----------------
// LDS-staged entry list + 8x-unrolled independent value loads (max 512/bin)
__global__ __launch_bounds__(256) void gather_kernel(
    const int* __restrict__ offsets, const int* __restrict__ bin_vidx,
    const float* __restrict__ bin_score, const float* __restrict__ value_w,
    float* __restrict__ out)
{
    __shared__ int   svidx[512];
    __shared__ float sscore[512];
    int bin = blockIdx.x;            // b*2048 + t
    int tid = threadIdx.x;
    int beg = offsets[bin], cnt = offsets[bin + 1] - beg;
    for (int n = tid; n < cnt; n += 256) {
        svidx[n]  = bin_vidx[beg + n];
        sscore[n] = bin_score[beg + n];
    }
    __syncthreads();

    const int c = tid * 2;
    float accx = 0.f, accy = 0.f;
    int n = 0;
    for (; n + 8 <= cnt; n += 8) {
        int vi[8]; float sc[8]; float2 vv[8];
        #pragma unroll
        for (int k = 0; k < 8; k++) { vi[k] = svidx[n+k]; sc[k] = sscore[n+k]; }
        #pragma unroll
        for (int k = 0; k < 8; k++)
            vv[k] = *(const float2*)&value_w[(size_t)vi[k] * DOUTc + c];
        #pragma unroll
        for (int k = 0; k < 8; k++) { accx += sc[k]*vv[k].x; accy += sc[k]*vv[k].y; }
    }
    for (; n < cnt; n++) {
        int v = svidx[n]; float sc = sscore[n];
        float2 a = *(const float2*)&value_w[(size_t)v * DOUTc + c];
        accx += sc*a.x; accy += sc*a.y;
    }
    float2 res; res.x = accx; res.y = accy;
    *(float2*)&out[(size_t)bin * DOUTc + c] = res;
}

// ---------------- launch ----------------
extern "C" void kernel_launch(void* const* d_in, const int* in_sizes, int n_in,
                              void* d_out, int out_size, void* d_ws, size_t ws_size,
                              hipStream_t stream)
{
    const float* x       = (const float*)d_in[0];
    const float* conv_w  = (const float*)d_in[1];
    const float* conv_b  = (const float*)d_in[2];
    const float* lin_w   = (const float*)d_in[3];
    const float* lin_b   = (const float*)d_in[4];
    const float* rowkeys = (const float*)d_in[5];
    const float* colkeys = (const float*)d_in[6];
    const float* value_w = (const float*)d_in[7];
    float* out = (float*)d_out;

    constexpr size_t MB = 1024*1024;
    char* w = (char*)d_ws;
    // Ctmp [0,40MB) overlays y1/y2/y3/w1/w2/w3 (dead after qgemm)
    float*          Ctmp = (float*)(w);                  // 40 MB @ 0
    unsigned short* y1   = (unsigned short*)(w);         //  8 MB @ 0
    unsigned short* y2   = (unsigned short*)(w +  8*MB); //  8 MB
    unsigned short* y3   = (unsigned short*)(w + 16*MB); //  8 MB
    unsigned short* w1   = (unsigned short*)(w + 24*MB); //  2 MB
    unsigned short* w2   = (unsigned short*)(w + 26*MB); //  2 MB
    unsigned short* w3   = (unsigned short*)(w + 28*MB); //  2 MB
    unsigned short* q1   = (unsigned short*)(w + 40*MB); //  8 MB
    unsigned short* q2   = (unsigned short*)(w + 48*MB); //  8 MB
    unsigned short* q3   = (unsigned short*)(w + 56*MB); //  8 MB
    unsigned short* k1   = (unsigned short*)(w + 64*MB); //  1.25 MB
    unsigned short* k2   = (unsigned short*)(w + 66*MB); //  1.25 MB
    unsigned short* k3   = (unsigned short*)(w + 68*MB); //  1.25 MB
    float*          s    = (float*)(w + 70*MB);          //  8 MB
    int*            cidx = (int*)  (w + 78*MB);          //  64 KB
    int*            tk_j = (int*)  (w + 79*MB);          //  1 MB
    int*            tk_v = (int*)  (w + 80*MB);          //  1 MB
    float*          tk_s = (float*)(w + 81*MB);          //  1 MB
    int*            counts    = (int*)  (w + 82*MB);          // 16 KB
    int*            offsets   = (int*)  (w + 82*MB + 32768);  // 16 KB + 4
    int*            fillctr   = (int*)  (w + 82*MB + 65536);  // 16 KB
    int*            bin_vidx  = (int*)  (w + 82*MB + 131072); // 1 MB
    float*          bin_score = (float*)(w + 82*MB + 131072 + 1048576); // 1 MB

    // 1. conv -> y h/m/l
    conv_kernel<<<(Bc*Tc*Cc)/256, 256, 0, stream>>>(x, conv_w, conv_b, y1, y2, y3);
    // 2. convert lin_w, keys
    convw_kernel<<<(QDc*Cc)/256, 256, 0, stream>>>(lin_w, w1, w2, w3);
    convkeys_kernel<<<Hc*NKEYS, 256, 0, stream>>>(rowkeys, colkeys, k1, k2, k3);
    // 3. query GEMM -> q h/m/l (flat 256 blocks, XCD-swizzled)
    qgemm_kernel<<<256, 512, 0, stream>>>(
        y1, y2, y3, w1, w2, w3, lin_b, q1, q2, q3);
    // 4. score GEMM -> Ctmp (flat 640 blocks, XCD-swizzled)
    sgemm_kernel<<<640, 512, 0, stream>>>(
        q1, q2, q3, k1, k2, k3, Ctmp);
    // 5. col max + s
    colmax_kernel<<<(Bc*Hc*Tc)/4, 256, 0, stream>>>(Ctmp, s, cidx);
    // 6. topk (wave-per-row, register-resident)
    topk_kernel<<<Bc*Hc*BLKc/4, 256, 0, stream>>>(s, cidx, tk_j, tk_v, tk_s);
    // 7. bin: zero (counts+offsets+fillctr in one launch), count, scan, fill
    zero_bins_kernel<<<(96*1024/4 + 255)/256, 256, 0, stream>>>(counts, 96*1024/4);
    count_kernel<<<NSEL/256, 256, 0, stream>>>(tk_j, counts);
    scan_kernel<<<1, 256, 0, stream>>>(counts, offsets);
    fill_kernel<<<NSEL/256, 256, 0, stream>>>(tk_j, tk_v, tk_s, offsets,
                                              fillctr, bin_vidx, bin_score);
    // 8. gather
    gather_kernel<<<NBINS, 256, 0, stream>>>(offsets, bin_vidx, bin_score,
                                             value_w, out);
}